// Round 3
// baseline (571.266 us; speedup 1.0000x reference)
//
#include <hip/hip_runtime.h>
#include <stdint.h>

#define B_ 4
#define D_ 256
#define N_ 4096
#define K_ 8192
#define Q_ (B_*N_)   // 16384 queries

typedef __attribute__((ext_vector_type(8))) short bf16x8;
typedef __attribute__((ext_vector_type(8))) unsigned short u16x8;
typedef __attribute__((ext_vector_type(16))) float f32x16;

__device__ __forceinline__ unsigned short f32_to_bf16(float f) {
  unsigned u = __float_as_uint(f);
  unsigned r = 0x7FFFu + ((u >> 16) & 1u);
  return (unsigned short)((u + r) >> 16);
}
__device__ __forceinline__ float bf16_to_f32(unsigned short h) {
  return __uint_as_float(((unsigned)h) << 16);
}

// async global->LDS, 16B per lane; LDS dest is wave-uniform base + lane*16
__device__ __forceinline__ void gl_lds16(const void* g, void* l) {
  __builtin_amdgcn_global_load_lds(
      (const __attribute__((address_space(1))) unsigned int*)g,
      (__attribute__((address_space(3))) unsigned int*)l, 16, 0, 0);
}

// Transpose x [B, D, N] -> xh/xl [Q=B*N, D] bf16 hi/lo split.
// Block = 64 d x 64 n tile, 256 threads. float4 reads, 16B/lane writes.
__global__ void prep_x_kernel(const float* __restrict__ x,
                              unsigned short* __restrict__ xh,
                              unsigned short* __restrict__ xl) {
  __shared__ float tile[64][65];   // pad 65: both phases <=2-way bank alias
  int b = blockIdx.z;
  int d0 = blockIdx.y * 64;
  int n0 = blockIdx.x * 64;
  int tid = threadIdx.x;

  // read phase: 4 passes x (16 rows x 64 cols as float4)
  int rr = tid >> 4;            // 0..15 (d-row within pass)
  int rc = (tid & 15) * 4;      // n-col
  const float* xp = x + ((size_t)b * D_ + d0) * N_ + n0;
#pragma unroll
  for (int p = 0; p < 4; ++p) {
    float4 v = *(const float4*)(xp + (size_t)(rr + 16 * p) * N_ + rc);
    tile[rr + 16 * p][rc + 0] = v.x;
    tile[rr + 16 * p][rc + 1] = v.y;
    tile[rr + 16 * p][rc + 2] = v.z;
    tile[rr + 16 * p][rc + 3] = v.w;
  }
  __syncthreads();

  // write phase: 2 passes; thread -> (n = nr, d = dc*8..dc*8+7)
  int nr = tid >> 3;            // 0..31
  int dc = tid & 7;             // 0..7
#pragma unroll
  for (int p = 0; p < 2; ++p) {
    int nn = nr + 32 * p;
    u16x8 h8, l8;
#pragma unroll
    for (int j = 0; j < 8; ++j) {
      float v = tile[dc * 8 + j][nn];
      unsigned short h = f32_to_bf16(v);
      h8[j] = h;
      l8[j] = f32_to_bf16(v - bf16_to_f32(h));
    }
    size_t q = (size_t)b * N_ + n0 + nn;
    *(u16x8*)(xh + q * D_ + d0 + dc * 8) = h8;
    *(u16x8*)(xl + q * D_ + d0 + dc * 8) = l8;
  }
}

// Split e [K, D] into bf16 hi/lo; compute 0.5*||e_k||^2; init keys.
__global__ void prep_e_kernel(const float* __restrict__ e,
                              unsigned short* __restrict__ eh,
                              unsigned short* __restrict__ el,
                              float* __restrict__ e2h,
                              unsigned long long* __restrict__ keys) {
  int k = blockIdx.x;
  int d = threadIdx.x;  // 256 threads
  if (d < 2) keys[(size_t)k * 2 + d] = ~0ull;  // Q_ = 2*K_
  float v = e[(size_t)k * D_ + d];
  unsigned short h = f32_to_bf16(v);
  unsigned short l = f32_to_bf16(v - bf16_to_f32(h));
  eh[(size_t)k * D_ + d] = h;
  el[(size_t)k * D_ + d] = l;
  float s = v * v;
#pragma unroll
  for (int off = 32; off > 0; off >>= 1) s += __shfl_down(s, off, 64);
  __shared__ float ws4[4];
  if ((threadIdx.x & 63) == 0) ws4[threadIdx.x >> 6] = s;
  __syncthreads();
  if (threadIdx.x == 0) e2h[k] = 0.5f * (ws4[0] + ws4[1] + ws4[2] + ws4[3]);
}

// Main: block = 256 queries x 1024 codes (K-split 8), 8 waves x 32 queries.
// grid 512 -> 2 blocks/CU (launch_bounds(512,4)); ks = blk&7 pins each
// K-split to one XCD (e-range L2-resident). Per chunk: 32 codes x 256 d
// (hi+lo) staged via global_load_lds, XOR-swizzled; 48 MFMAs/wave/chunk.
__global__ __launch_bounds__(512, 4) void vq_main_kernel(
    const unsigned short* __restrict__ xh, const unsigned short* __restrict__ xl,
    const unsigned short* __restrict__ eh, const unsigned short* __restrict__ el,
    const float* __restrict__ e2h, unsigned long long* __restrict__ keys) {
  // [buf][half][code*256 + swizzled runs]; 64 KB, dense (DMA-compatible).
  // run g of code c lives at 16B-slot (g ^ (c&31)) within the code's 512 B row.
  __shared__ __attribute__((aligned(16))) unsigned short Bs[2][2][32 * 256];

  const int tid = threadIdx.x;
  const int w = tid >> 6;       // wave 0..7
  const int lane = tid & 63;
  const int l = lane & 31;      // spatial index (code col / query row)
  const int hi = lane >> 5;     // k-group half

  const int qt = blockIdx.x >> 3;
  const int ks8 = blockIdx.x & 7;
  const int q0 = qt * 256;
  const int kbase = ks8 * 1024;
  const int qw = q0 + w * 32;

  // Persistent A fragments: 32 queries x 256 d, hi+lo. A[m=lane&31][k=hi*8+j].
  bf16x8 ah[16], al[16];
  {
    const unsigned short* pa = xh + (size_t)(qw + l) * D_ + hi * 8;
    const unsigned short* pb = xl + (size_t)(qw + l) * D_ + hi * 8;
#pragma unroll
    for (int kc16 = 0; kc16 < 16; ++kc16) {
      ah[kc16] = *(const bf16x8*)(pa + kc16 * 16);
      al[kc16] = *(const bf16x8*)(pb + kc16 * 16);
    }
  }

  float rminv[16];
  int rmini[16];
#pragma unroll
  for (int r = 0; r < 16; ++r) { rminv[r] = __builtin_inff(); rmini[r] = 0; }

  // Stage chunk ch into buf: wave w loads codes [w*4, w*4+4), both halves.
  auto stage = [&](int ch, int buf) {
    const int kc = kbase + ch * 32;
#pragma unroll
    for (int p = 0; p < 2; ++p) {
      const int c0 = w * 4 + p * 2;
      const int c = c0 + hi;
      const int g = l ^ (c & 31);
      const size_t srcoff = (size_t)(kc + c) * D_ + g * 8;
      gl_lds16(eh + srcoff, &Bs[buf][0][c0 * 256]);
      gl_lds16(el + srcoff, &Bs[buf][1][c0 * 256]);
    }
  };

  stage(0, 0);

#pragma unroll 1
  for (int ch = 0; ch < 32; ++ch) {
    const int buf = ch & 1;
    __syncthreads();                    // drains DMA for chunk ch
    if (ch + 1 < 32) stage(ch + 1, buf ^ 1);
    const int kc = kbase + ch * 32;
    const float e2v = e2h[kc + l];

    f32x16 acc;
#pragma unroll
    for (int r = 0; r < 16; ++r) acc[r] = 0.f;

#pragma unroll
    for (int ks = 0; ks < 16; ++ks) {
      const int pos = (((ks * 2 + hi) ^ l) * 8);
      bf16x8 bh = *(const bf16x8*)&Bs[buf][0][l * 256 + pos];
      bf16x8 bl = *(const bf16x8*)&Bs[buf][1][l * 256 + pos];
      acc = __builtin_amdgcn_mfma_f32_32x32x16_bf16(ah[ks], bh, acc, 0, 0, 0);
      acc = __builtin_amdgcn_mfma_f32_32x32x16_bf16(ah[ks], bl, acc, 0, 0, 0);
      acc = __builtin_amdgcn_mfma_f32_32x32x16_bf16(al[ks], bh, acc, 0, 0, 0);
    }

    const int kidx = kc + l;  // all 16 acc regs share the same code column
#pragma unroll
    for (int r = 0; r < 16; ++r) {
      float dv = e2v - acc[r];
      bool better = dv < rminv[r];
      rminv[r] = better ? dv : rminv[r];
      rmini[r] = better ? kidx : rmini[r];
    }
  }

  // Reduce over 32 code-columns (butterfly), then cross-block merge via
  // packed (sortable-float<<32 | idx) u64 atomicMin.
#pragma unroll
  for (int r = 0; r < 16; ++r) {
    float bv = rminv[r];
    int bi = rmini[r];
#pragma unroll
    for (int xm = 1; xm <= 16; xm <<= 1) {
      float ov = __shfl_xor(bv, xm, 64);
      int oi = __shfl_xor(bi, xm, 64);
      if (ov < bv || (ov == bv && oi < bi)) { bv = ov; bi = oi; }
    }
    if (l == 0) {
      const int m = (r & 3) + 8 * (r >> 2) + 4 * hi;  // C/D row mapping (m74/m101)
      const int qq = qw + m;
      unsigned su = __float_as_uint(bv);
      su ^= (unsigned)(((int)su >> 31) | 0x80000000u);
      unsigned long long key = ((unsigned long long)su << 32) | (unsigned)bi;
      atomicMin(keys + qq, key);
    }
  }
}

// out[b][d][n] = e[code[b,n]][d]; thread handles 4 consecutive n (float4 store)
__global__ void decode_kernel(const unsigned long long* __restrict__ keys,
                              const float* __restrict__ e,
                              float* __restrict__ out) {
  size_t gid = (size_t)blockIdx.x * 256 + threadIdx.x;  // Q_*D_/4 total
  int nq = (int)(gid % (N_ / 4));
  int rest = (int)(gid / (N_ / 4));
  int d = rest % D_;
  int b = rest / D_;
  int n0 = nq * 4;
  const unsigned long long* kp = keys + (size_t)b * N_ + n0;
  float4 o;
  o.x = e[(size_t)(unsigned)(kp[0] & 0xFFFFFFFFull) * D_ + d];
  o.y = e[(size_t)(unsigned)(kp[1] & 0xFFFFFFFFull) * D_ + d];
  o.z = e[(size_t)(unsigned)(kp[2] & 0xFFFFFFFFull) * D_ + d];
  o.w = e[(size_t)(unsigned)(kp[3] & 0xFFFFFFFFull) * D_ + d];
  *(float4*)(out + ((size_t)b * D_ + d) * N_ + n0) = o;
}

extern "C" void kernel_launch(void* const* d_in, const int* in_sizes, int n_in,
                              void* d_out, int out_size, void* d_ws, size_t ws_size,
                              hipStream_t stream) {
  const float* x = (const float*)d_in[0];
  const float* e = (const float*)d_in[1];
  float* out = (float*)d_out;

  // workspace layout (~24.2 MB)
  char* wksp = (char*)d_ws;
  unsigned short* xh = (unsigned short*)wksp;                   // 8 MB
  unsigned short* xl = xh + (size_t)Q_ * D_;                    // 8 MB
  unsigned short* eh = xl + (size_t)Q_ * D_;                    // 4 MB
  unsigned short* el = eh + (size_t)K_ * D_;                    // 4 MB
  float* e2h = (float*)(el + (size_t)K_ * D_);                  // 32 KB
  unsigned long long* keys = (unsigned long long*)(e2h + K_);   // 128 KB

  prep_x_kernel<<<dim3(N_ / 64, D_ / 64, B_), 256, 0, stream>>>(x, xh, xl);
  prep_e_kernel<<<K_, 256, 0, stream>>>(e, eh, el, e2h, keys);
  vq_main_kernel<<<512, 512, 0, stream>>>(xh, xl, eh, el, e2h, keys);
  decode_kernel<<<(Q_ * D_) / 1024, 256, 0, stream>>>(keys, e, out);
}

// Round 4
// 269.512 us; speedup vs baseline: 2.1196x; 2.1196x over previous
//
#include <hip/hip_runtime.h>
#include <stdint.h>

#define B_ 4
#define D_ 256
#define N_ 4096
#define K_ 8192
#define Q_ (B_*N_)   // 16384 queries

typedef __attribute__((ext_vector_type(8))) short bf16x8;
typedef __attribute__((ext_vector_type(8))) unsigned short u16x8;
typedef __attribute__((ext_vector_type(16))) float f32x16;

__device__ __forceinline__ unsigned short f32_to_bf16(float f) {
  unsigned u = __float_as_uint(f);
  unsigned r = 0x7FFFu + ((u >> 16) & 1u);
  return (unsigned short)((u + r) >> 16);
}
__device__ __forceinline__ float bf16_to_f32(unsigned short h) {
  return __uint_as_float(((unsigned)h) << 16);
}

// async global->LDS, 16B per lane; LDS dest is wave-uniform base + lane*16
__device__ __forceinline__ void gl_lds16(const void* g, void* l) {
  __builtin_amdgcn_global_load_lds(
      (const __attribute__((address_space(1))) unsigned int*)g,
      (__attribute__((address_space(3))) unsigned int*)l, 16, 0, 0);
}

// Transpose x [B, D, N] -> xh/xl [Q=B*N, D] bf16 hi/lo split.
// Block = 64 d x 64 n tile, 256 threads. float4 reads, 16B/lane writes.
__global__ void prep_x_kernel(const float* __restrict__ x,
                              unsigned short* __restrict__ xh,
                              unsigned short* __restrict__ xl) {
  __shared__ float tile[64][65];   // pad 65: both phases <=2-way bank alias
  int b = blockIdx.z;
  int d0 = blockIdx.y * 64;
  int n0 = blockIdx.x * 64;
  int tid = threadIdx.x;

  int rr = tid >> 4;            // 0..15 (d-row within pass)
  int rc = (tid & 15) * 4;      // n-col
  const float* xp = x + ((size_t)b * D_ + d0) * N_ + n0;
#pragma unroll
  for (int p = 0; p < 4; ++p) {
    float4 v = *(const float4*)(xp + (size_t)(rr + 16 * p) * N_ + rc);
    tile[rr + 16 * p][rc + 0] = v.x;
    tile[rr + 16 * p][rc + 1] = v.y;
    tile[rr + 16 * p][rc + 2] = v.z;
    tile[rr + 16 * p][rc + 3] = v.w;
  }
  __syncthreads();

  int nr = tid >> 3;            // 0..31
  int dc = tid & 7;             // 0..7
#pragma unroll
  for (int p = 0; p < 2; ++p) {
    int nn = nr + 32 * p;
    u16x8 h8, l8;
#pragma unroll
    for (int j = 0; j < 8; ++j) {
      float v = tile[dc * 8 + j][nn];
      unsigned short h = f32_to_bf16(v);
      h8[j] = h;
      l8[j] = f32_to_bf16(v - bf16_to_f32(h));
    }
    size_t q = (size_t)b * N_ + n0 + nn;
    *(u16x8*)(xh + q * D_ + d0 + dc * 8) = h8;
    *(u16x8*)(xl + q * D_ + d0 + dc * 8) = l8;
  }
}

// Split e [K, D] into bf16 hi/lo; 0.5*||e_k||^2; init keys.
// 8 codebook rows per block (grid K_/8), vectorized: thread=(kk, d8).
__global__ void prep_e_kernel(const float* __restrict__ e,
                              unsigned short* __restrict__ eh,
                              unsigned short* __restrict__ el,
                              float* __restrict__ e2h,
                              unsigned long long* __restrict__ keys) {
  int tid = threadIdx.x;
  int k = blockIdx.x * 8 + (tid >> 5);
  int d = (tid & 31) * 8;
  if (tid < 16) keys[(size_t)blockIdx.x * 16 + tid] = ~0ull;  // Q_ = 16*(K_/8)
  const float* ep = e + (size_t)k * D_ + d;
  float4 v0 = *(const float4*)(ep);
  float4 v1 = *(const float4*)(ep + 4);
  float vv[8] = {v0.x, v0.y, v0.z, v0.w, v1.x, v1.y, v1.z, v1.w};
  u16x8 h8, l8;
  float s = 0.f;
#pragma unroll
  for (int j = 0; j < 8; ++j) {
    unsigned short h = f32_to_bf16(vv[j]);
    h8[j] = h;
    l8[j] = f32_to_bf16(vv[j] - bf16_to_f32(h));
    s += vv[j] * vv[j];
  }
  *(u16x8*)(eh + (size_t)k * D_ + d) = h8;
  *(u16x8*)(el + (size_t)k * D_ + d) = l8;
#pragma unroll
  for (int off = 16; off > 0; off >>= 1) s += __shfl_xor(s, off, 64);
  if ((tid & 31) == 0) e2h[k] = 0.5f * s;
}

// Main: block = 128 queries x 2048 codes (K-split 4), 4 waves x 32 queries,
// grid 512 -> 2 blocks/CU. The two co-resident blocks have independent
// barriers, so their LDS-read and MFMA phases anti-align (pipe overlap).
// Per chunk: 32 codes x 256 d (hi+lo) via global_load_lds, XOR-swizzled;
// 48 MFMAs (32x32x16) per wave per chunk; one barrier per chunk.
__global__ __launch_bounds__(256, 2) void vq_main_kernel(
    const unsigned short* __restrict__ xh, const unsigned short* __restrict__ xl,
    const unsigned short* __restrict__ eh, const unsigned short* __restrict__ el,
    const float* __restrict__ e2h, unsigned long long* __restrict__ keys) {
  // [buf][half][code*256 + swizzled runs]; 64 KB, dense (DMA-compatible).
  // run g of code c lives at 16B-slot (g ^ (c&31)) within the code's 512 B row.
  __shared__ __attribute__((aligned(16))) unsigned short Bs[2][2][32 * 256];

  const int tid = threadIdx.x;
  const int w = tid >> 6;       // wave 0..3
  const int lane = tid & 63;
  const int l = lane & 31;      // spatial index (code col / query row)
  const int hi = lane >> 5;     // k-group half

  const int qt = blockIdx.x >> 2;
  const int ks4 = blockIdx.x & 3;
  const int q0 = qt * 128;
  const int kbase = ks4 * 2048;
  const int qw = q0 + w * 32;

  // Persistent A fragments: 32 queries x 256 d, hi+lo. A[m=lane&31][k=hi*8+j].
  // These land in AGPRs (unified file); ~236 regs/wave total -> 2 waves/SIMD.
  bf16x8 ah[16], al[16];
  {
    const unsigned short* pa = xh + (size_t)(qw + l) * D_ + hi * 8;
    const unsigned short* pb = xl + (size_t)(qw + l) * D_ + hi * 8;
#pragma unroll
    for (int kc16 = 0; kc16 < 16; ++kc16) {
      ah[kc16] = *(const bf16x8*)(pa + kc16 * 16);
      al[kc16] = *(const bf16x8*)(pb + kc16 * 16);
    }
  }

  float rminv[16];
  int rmini[16];
#pragma unroll
  for (int r = 0; r < 16; ++r) { rminv[r] = __builtin_inff(); rmini[r] = 0; }

  // Stage chunk ch into buf: wave w loads codes [w*8, w*8+8), both halves.
  auto stage = [&](int ch, int buf) {
    const int kc = kbase + ch * 32;
#pragma unroll
    for (int p = 0; p < 4; ++p) {
      const int c0 = w * 8 + p * 2;
      const int c = c0 + hi;
      const int g = l ^ (c & 31);
      const size_t srcoff = (size_t)(kc + c) * D_ + g * 8;
      gl_lds16(eh + srcoff, &Bs[buf][0][c0 * 256]);
      gl_lds16(el + srcoff, &Bs[buf][1][c0 * 256]);
    }
  };

  stage(0, 0);

#pragma unroll 1
  for (int ch = 0; ch < 64; ++ch) {
    const int buf = ch & 1;
    __syncthreads();                    // drains DMA for chunk ch
    if (ch + 1 < 64) stage(ch + 1, buf ^ 1);
    const int kc = kbase + ch * 32;
    const float e2v = e2h[kc + l];

    f32x16 acc;
#pragma unroll
    for (int r = 0; r < 16; ++r) acc[r] = 0.f;

#pragma unroll
    for (int ks = 0; ks < 16; ++ks) {
      const int pos = (((ks * 2 + hi) ^ l) * 8);
      bf16x8 bh = *(const bf16x8*)&Bs[buf][0][l * 256 + pos];
      bf16x8 bl = *(const bf16x8*)&Bs[buf][1][l * 256 + pos];
      acc = __builtin_amdgcn_mfma_f32_32x32x16_bf16(ah[ks], bh, acc, 0, 0, 0);
      acc = __builtin_amdgcn_mfma_f32_32x32x16_bf16(ah[ks], bl, acc, 0, 0, 0);
      acc = __builtin_amdgcn_mfma_f32_32x32x16_bf16(al[ks], bh, acc, 0, 0, 0);
    }

    const int kidx = kc + l;  // all 16 acc regs share the same code column
#pragma unroll
    for (int r = 0; r < 16; ++r) {
      float dv = e2v - acc[r];
      bool better = dv < rminv[r];
      rminv[r] = better ? dv : rminv[r];
      rmini[r] = better ? kidx : rmini[r];
    }
  }

  // Reduce over 32 code-columns (butterfly), then cross-block merge via
  // packed (sortable-float<<32 | idx) u64 atomicMin.
#pragma unroll
  for (int r = 0; r < 16; ++r) {
    float bv = rminv[r];
    int bi = rmini[r];
#pragma unroll
    for (int xm = 1; xm <= 16; xm <<= 1) {
      float ov = __shfl_xor(bv, xm, 64);
      int oi = __shfl_xor(bi, xm, 64);
      if (ov < bv || (ov == bv && oi < bi)) { bv = ov; bi = oi; }
    }
    if (l == 0) {
      const int m = (r & 3) + 8 * (r >> 2) + 4 * hi;  // C/D row mapping (m74/m101)
      const int qq = qw + m;
      unsigned su = __float_as_uint(bv);
      su ^= (unsigned)(((int)su >> 31) | 0x80000000u);
      unsigned long long key = ((unsigned long long)su << 32) | (unsigned)bi;
      atomicMin(keys + qq, key);
    }
  }
}

// out[b][d][n] = e[code[b,n]][d]; thread handles 4 consecutive n (float4 store)
__global__ void decode_kernel(const unsigned long long* __restrict__ keys,
                              const float* __restrict__ e,
                              float* __restrict__ out) {
  size_t gid = (size_t)blockIdx.x * 256 + threadIdx.x;  // Q_*D_/4 total
  int nq = (int)(gid % (N_ / 4));
  int rest = (int)(gid / (N_ / 4));
  int d = rest % D_;
  int b = rest / D_;
  int n0 = nq * 4;
  const unsigned long long* kp = keys + (size_t)b * N_ + n0;
  float4 o;
  o.x = e[(size_t)(unsigned)(kp[0] & 0xFFFFFFFFull) * D_ + d];
  o.y = e[(size_t)(unsigned)(kp[1] & 0xFFFFFFFFull) * D_ + d];
  o.z = e[(size_t)(unsigned)(kp[2] & 0xFFFFFFFFull) * D_ + d];
  o.w = e[(size_t)(unsigned)(kp[3] & 0xFFFFFFFFull) * D_ + d];
  *(float4*)(out + ((size_t)b * D_ + d) * N_ + n0) = o;
}

extern "C" void kernel_launch(void* const* d_in, const int* in_sizes, int n_in,
                              void* d_out, int out_size, void* d_ws, size_t ws_size,
                              hipStream_t stream) {
  const float* x = (const float*)d_in[0];
  const float* e = (const float*)d_in[1];
  float* out = (float*)d_out;

  // workspace layout (~24.2 MB)
  char* wksp = (char*)d_ws;
  unsigned short* xh = (unsigned short*)wksp;                   // 8 MB
  unsigned short* xl = xh + (size_t)Q_ * D_;                    // 8 MB
  unsigned short* eh = xl + (size_t)Q_ * D_;                    // 4 MB
  unsigned short* el = eh + (size_t)K_ * D_;                    // 4 MB
  float* e2h = (float*)(el + (size_t)K_ * D_);                  // 32 KB
  unsigned long long* keys = (unsigned long long*)(e2h + K_);   // 128 KB

  prep_x_kernel<<<dim3(N_ / 64, D_ / 64, B_), 256, 0, stream>>>(x, xh, xl);
  prep_e_kernel<<<K_ / 8, 256, 0, stream>>>(e, eh, el, e2h, keys);
  vq_main_kernel<<<512, 256, 0, stream>>>(xh, xl, eh, el, e2h, keys);
  decode_kernel<<<(Q_ * D_) / 1024, 256, 0, stream>>>(keys, e, out);
}

// Round 5
// 264.105 us; speedup vs baseline: 2.1630x; 1.0205x over previous
//
#include <hip/hip_runtime.h>
#include <stdint.h>

#define B_ 4
#define D_ 256
#define N_ 4096
#define K_ 8192
#define Q_ (B_*N_)   // 16384 queries

typedef __attribute__((ext_vector_type(8))) short bf16x8;
typedef __attribute__((ext_vector_type(8))) unsigned short u16x8;
typedef __attribute__((ext_vector_type(16))) float f32x16;

__device__ __forceinline__ unsigned short f32_to_bf16(float f) {
  unsigned u = __float_as_uint(f);
  unsigned r = 0x7FFFu + ((u >> 16) & 1u);
  return (unsigned short)((u + r) >> 16);
}
__device__ __forceinline__ float bf16_to_f32(unsigned short h) {
  return __uint_as_float(((unsigned)h) << 16);
}

// async global->LDS, 16B per lane; LDS dest is wave-uniform base + lane*16
__device__ __forceinline__ void gl_lds16(const void* g, void* l) {
  __builtin_amdgcn_global_load_lds(
      (const __attribute__((address_space(1))) unsigned int*)g,
      (__attribute__((address_space(3))) unsigned int*)l, 16, 0, 0);
}

// Transpose x [B, D, N] -> xh/xl [Q=B*N, D] bf16 hi/lo split.
__global__ void prep_x_kernel(const float* __restrict__ x,
                              unsigned short* __restrict__ xh,
                              unsigned short* __restrict__ xl) {
  __shared__ float tile[64][65];
  int b = blockIdx.z;
  int d0 = blockIdx.y * 64;
  int n0 = blockIdx.x * 64;
  int tid = threadIdx.x;

  int rr = tid >> 4;
  int rc = (tid & 15) * 4;
  const float* xp = x + ((size_t)b * D_ + d0) * N_ + n0;
#pragma unroll
  for (int p = 0; p < 4; ++p) {
    float4 v = *(const float4*)(xp + (size_t)(rr + 16 * p) * N_ + rc);
    tile[rr + 16 * p][rc + 0] = v.x;
    tile[rr + 16 * p][rc + 1] = v.y;
    tile[rr + 16 * p][rc + 2] = v.z;
    tile[rr + 16 * p][rc + 3] = v.w;
  }
  __syncthreads();

  int nr = tid >> 3;
  int dc = tid & 7;
#pragma unroll
  for (int p = 0; p < 2; ++p) {
    int nn = nr + 32 * p;
    u16x8 h8, l8;
#pragma unroll
    for (int j = 0; j < 8; ++j) {
      float v = tile[dc * 8 + j][nn];
      unsigned short h = f32_to_bf16(v);
      h8[j] = h;
      l8[j] = f32_to_bf16(v - bf16_to_f32(h));
    }
    size_t q = (size_t)b * N_ + n0 + nn;
    *(u16x8*)(xh + q * D_ + d0 + dc * 8) = h8;
    *(u16x8*)(xl + q * D_ + d0 + dc * 8) = l8;
  }
}

// Split e [K, D] into bf16 hi/lo; 0.5*||e_k||^2; init keys.
__global__ void prep_e_kernel(const float* __restrict__ e,
                              unsigned short* __restrict__ eh,
                              unsigned short* __restrict__ el,
                              float* __restrict__ e2h,
                              unsigned long long* __restrict__ keys) {
  int tid = threadIdx.x;
  int k = blockIdx.x * 8 + (tid >> 5);
  int d = (tid & 31) * 8;
  if (tid < 16) keys[(size_t)blockIdx.x * 16 + tid] = ~0ull;  // Q_ = 16*(K_/8)
  const float* ep = e + (size_t)k * D_ + d;
  float4 v0 = *(const float4*)(ep);
  float4 v1 = *(const float4*)(ep + 4);
  float vv[8] = {v0.x, v0.y, v0.z, v0.w, v1.x, v1.y, v1.z, v1.w};
  u16x8 h8, l8;
  float s = 0.f;
#pragma unroll
  for (int j = 0; j < 8; ++j) {
    unsigned short h = f32_to_bf16(vv[j]);
    h8[j] = h;
    l8[j] = f32_to_bf16(vv[j] - bf16_to_f32(h));
    s += vv[j] * vv[j];
  }
  *(u16x8*)(eh + (size_t)k * D_ + d) = h8;
  *(u16x8*)(el + (size_t)k * D_ + d) = l8;
#pragma unroll
  for (int off = 16; off > 0; off >>= 1) s += __shfl_xor(s, off, 64);
  if ((tid & 31) == 0) e2h[k] = 0.5f * s;
}

// Main: block = 256 queries x 2048 codes (K-split 4), 4 waves x M=64 queries.
// grid 256 -> 1 block/CU, 1 wave/SIMD; ks = blk&3 pins each e-slice (2 MB)
// to one XCD's L2. Each (bh,bl) LDS read pair feeds 6 MFMAs (2 M-blocks x
// 3 precision terms) -> LDS pipe at 50%, MFMA pipe is the long pole.
__global__ __launch_bounds__(256, 1) void vq_main_kernel(
    const unsigned short* __restrict__ xh, const unsigned short* __restrict__ xl,
    const unsigned short* __restrict__ eh, const unsigned short* __restrict__ el,
    const float* __restrict__ e2h, unsigned long long* __restrict__ keys) {
  // [buf][half][code*256 + swizzled runs]; 64 KB, dense (DMA-compatible).
  // run g of code c lives at 16B-slot (g ^ (c&31)) within the code's 512 B row.
  __shared__ __attribute__((aligned(16))) unsigned short Bs[2][2][32 * 256];

  const int tid = threadIdx.x;
  const int w = tid >> 6;       // wave 0..3
  const int lane = tid & 63;
  const int l = lane & 31;      // spatial index (code col / query row)
  const int hi = lane >> 5;     // k-group half

  const int qt = blockIdx.x >> 2;
  const int ks4 = blockIdx.x & 3;
  const int q0 = qt * 256;
  const int kbase = ks4 * 2048;
  const int qw = q0 + w * 64;

  // Persistent A fragments: 2 M-blocks x 32 queries x 256 d, hi+lo (256 regs).
  bf16x8 ah[2][16], al[2][16];
#pragma unroll
  for (int mb = 0; mb < 2; ++mb) {
    const unsigned short* pa = xh + (size_t)(qw + mb * 32 + l) * D_ + hi * 8;
    const unsigned short* pb = xl + (size_t)(qw + mb * 32 + l) * D_ + hi * 8;
#pragma unroll
    for (int k16 = 0; k16 < 16; ++k16) {
      ah[mb][k16] = *(const bf16x8*)(pa + k16 * 16);
      al[mb][k16] = *(const bf16x8*)(pb + k16 * 16);
    }
  }

  float rminv[2][16];
  int rmini[2][16];
#pragma unroll
  for (int mb = 0; mb < 2; ++mb)
#pragma unroll
    for (int r = 0; r < 16; ++r) { rminv[mb][r] = __builtin_inff(); rmini[mb][r] = 0; }

  // Stage chunk ch into buf: wave w loads codes [w*8, w*8+8), both halves.
  auto stage = [&](int ch, int buf) {
    const int kc = kbase + ch * 32;
#pragma unroll
    for (int p = 0; p < 4; ++p) {
      const int c0 = w * 8 + p * 2;
      const int c = c0 + hi;
      const int g = l ^ (c & 31);
      const size_t srcoff = (size_t)(kc + c) * D_ + g * 8;
      gl_lds16(eh + srcoff, &Bs[buf][0][c0 * 256]);
      gl_lds16(el + srcoff, &Bs[buf][1][c0 * 256]);
    }
  };

  stage(0, 0);

#pragma unroll 1
  for (int ch = 0; ch < 64; ++ch) {
    const int buf = ch & 1;
    __syncthreads();                    // drains DMA for chunk ch
    if (ch + 1 < 64) stage(ch + 1, buf ^ 1);
    const int kc = kbase + ch * 32;
    const float e2v = e2h[kc + l];

    f32x16 acc0, acc1;
#pragma unroll
    for (int r = 0; r < 16; ++r) { acc0[r] = 0.f; acc1[r] = 0.f; }

#pragma unroll
    for (int ks = 0; ks < 16; ++ks) {
      const int pos = (((ks * 2 + hi) ^ l) * 8);
      bf16x8 bh = *(const bf16x8*)&Bs[buf][0][l * 256 + pos];
      bf16x8 bl = *(const bf16x8*)&Bs[buf][1][l * 256 + pos];
      // interleave acc0/acc1: dependent MFMAs are >=2 instrs apart (~64 cyc)
      acc0 = __builtin_amdgcn_mfma_f32_32x32x16_bf16(ah[0][ks], bh, acc0, 0, 0, 0);
      acc1 = __builtin_amdgcn_mfma_f32_32x32x16_bf16(ah[1][ks], bh, acc1, 0, 0, 0);
      acc0 = __builtin_amdgcn_mfma_f32_32x32x16_bf16(ah[0][ks], bl, acc0, 0, 0, 0);
      acc1 = __builtin_amdgcn_mfma_f32_32x32x16_bf16(ah[1][ks], bl, acc1, 0, 0, 0);
      acc0 = __builtin_amdgcn_mfma_f32_32x32x16_bf16(al[0][ks], bh, acc0, 0, 0, 0);
      acc1 = __builtin_amdgcn_mfma_f32_32x32x16_bf16(al[1][ks], bh, acc1, 0, 0, 0);
    }

    const int kidx = kc + l;
#pragma unroll
    for (int r = 0; r < 16; ++r) {
      float dv0 = e2v - acc0[r];
      bool b0 = dv0 < rminv[0][r];
      rminv[0][r] = b0 ? dv0 : rminv[0][r];
      rmini[0][r] = b0 ? kidx : rmini[0][r];
      float dv1 = e2v - acc1[r];
      bool b1 = dv1 < rminv[1][r];
      rminv[1][r] = b1 ? dv1 : rminv[1][r];
      rmini[1][r] = b1 ? kidx : rmini[1][r];
    }
  }

  // Reduce over 32 code-columns (butterfly), then cross-block merge via
  // packed (sortable-float<<32 | idx) u64 atomicMin.
#pragma unroll
  for (int mb = 0; mb < 2; ++mb) {
#pragma unroll
    for (int r = 0; r < 16; ++r) {
      float bv = rminv[mb][r];
      int bi = rmini[mb][r];
#pragma unroll
      for (int xm = 1; xm <= 16; xm <<= 1) {
        float ov = __shfl_xor(bv, xm, 64);
        int oi = __shfl_xor(bi, xm, 64);
        if (ov < bv || (ov == bv && oi < bi)) { bv = ov; bi = oi; }
      }
      if (l == 0) {
        const int m = (r & 3) + 8 * (r >> 2) + 4 * hi;  // C/D row map (m74/m101)
        const int qq = qw + mb * 32 + m;
        unsigned su = __float_as_uint(bv);
        su ^= (unsigned)(((int)su >> 31) | 0x80000000u);
        unsigned long long key = ((unsigned long long)su << 32) | (unsigned)bi;
        atomicMin(keys + qq, key);
      }
    }
  }
}

// Decode: block = (b, 64 n). Gather 64 code rows coalesced (float4/lane)
// into LDS, transpose, write out[b][d][n] in 256 B segments.
__global__ __launch_bounds__(256, 2) void decode_kernel(
    const unsigned long long* __restrict__ keys,
    const float* __restrict__ e, float* __restrict__ out) {
  __shared__ float tile[64][257];
  int b = blockIdx.x >> 6;
  int n0 = (blockIdx.x & 63) * 64;
  int tid = threadIdx.x;
  int w = tid >> 6, lane = tid & 63;

  // phase 1: wave w gathers rows w*16 .. w*16+15 (1 KB each, coalesced)
#pragma unroll
  for (int j = 0; j < 16; ++j) {
    int i = w * 16 + j;
    unsigned idx = (unsigned)(keys[(size_t)b * N_ + n0 + i] & 0xFFFFFFFFull);
    float4 v = *(const float4*)(e + (size_t)idx * D_ + lane * 4);
    *(float4*)&tile[i][lane * 4] = v;
  }
  __syncthreads();

  // phase 2: thread (nq=tid&15, dr=tid>>4); d = dr + p*16.
  // Stores: lanes 0..15 cover 64 consecutive n (256 B segments).
  int nq = tid & 15, dr = tid >> 4;
#pragma unroll
  for (int p = 0; p < 16; ++p) {
    int d = dr + p * 16;
    float4 o;
    o.x = tile[nq * 4 + 0][d];
    o.y = tile[nq * 4 + 1][d];
    o.z = tile[nq * 4 + 2][d];
    o.w = tile[nq * 4 + 3][d];
    *(float4*)(out + ((size_t)b * D_ + d) * N_ + n0 + nq * 4) = o;
  }
}

extern "C" void kernel_launch(void* const* d_in, const int* in_sizes, int n_in,
                              void* d_out, int out_size, void* d_ws, size_t ws_size,
                              hipStream_t stream) {
  const float* x = (const float*)d_in[0];
  const float* e = (const float*)d_in[1];
  float* out = (float*)d_out;

  // workspace layout (~24.2 MB)
  char* wksp = (char*)d_ws;
  unsigned short* xh = (unsigned short*)wksp;                   // 8 MB
  unsigned short* xl = xh + (size_t)Q_ * D_;                    // 8 MB
  unsigned short* eh = xl + (size_t)Q_ * D_;                    // 4 MB
  unsigned short* el = eh + (size_t)K_ * D_;                    // 4 MB
  float* e2h = (float*)(el + (size_t)K_ * D_);                  // 32 KB
  unsigned long long* keys = (unsigned long long*)(e2h + K_);   // 128 KB

  prep_x_kernel<<<dim3(N_ / 64, D_ / 64, B_), 256, 0, stream>>>(x, xh, xl);
  prep_e_kernel<<<K_ / 8, 256, 0, stream>>>(e, eh, el, e2h, keys);
  vq_main_kernel<<<256, 256, 0, stream>>>(xh, xl, eh, el, e2h, keys);
  decode_kernel<<<256, 256, 0, stream>>>(keys, e, out);
}